// Round 2
// baseline (1310.688 us; speedup 1.0000x reference)
//
#include <hip/hip_runtime.h>
#include <hip/hip_bf16.h>

// NeuralSpectralBlock1d on MI355X (gfx950)
// B=32, C=256, H=4096, PATCH=4, HEAD=8, DH=32, NT=4, NB=12
//
// wconv_kernel: enc_w ++ dec_w -> bf16 Wb[768][256]; weights -> float2 Wp[128][24]
// nsb_kernel: grid 2048 = 32 b * 64 col-chunks(64 h); block 512 (8 waves)
//   pass-1 GEMM: enc rows 0..511 (wave owns 64 rows = head wv), acc1[4][4]
//   per half hf (32 cols = 8 patches):
//     E-write (pk_bf16 dwords, XOR-swizzled) -> attn1 (all 64 lanes,
//     lane=(dh2,h,l), online softmax, shfl_xor(32) reduce) -> spectral
//     (channel-pair packed, angle-addition recurrence)
//   pass-2 GEMM (once, after hf0): dec rows 512..767, acc2[2][4]
//   D-write -> attn2 (all lanes, lane=(dh2,h,p)) -> +xp -> store
//
// LDS (62592 B):
//   pass1:  A1 [0,36864) 512 rows*72B ; B [36864,41472) 64 cols*72B (lives on)
//   epilog: E  [0,32768) 32 cols*256 words, kv-pair dwords, (d+4h+8(col&3))&31 swz
//           A2 [0,18432) pass-2 overlay ; D [18432,35328) 32 cols*132 words
//           LT [41472,58368) 8 patch * 4 l * 132 words ; QL [58368,62592) fp32 [h][l][33]

typedef __attribute__((ext_vector_type(8))) short short8;
typedef __attribute__((ext_vector_type(4))) float f32x4;

#define A1OFF 0
#define BOFF  36864
#define EOFF  0
#define A2OFF 0
#define DOFF  18432
#define LTOFF 41472
#define QLOFF 58368
#define SMEM_BYTES 62592

__device__ __forceinline__ unsigned int pk_bf16(float a, float b) {
  __hip_bfloat162 h = __float22bfloat162_rn(make_float2(a, b));
  unsigned int u; __builtin_memcpy(&u, &h, 4); return u;
}
__device__ __forceinline__ float blo(unsigned int u) { return __uint_as_float(u << 16); }
__device__ __forceinline__ float bhi(unsigned int u) { return __uint_as_float(u & 0xFFFF0000u); }

__global__ void wconv_kernel(const float* __restrict__ enc_w,
                             const float* __restrict__ dec_w,
                             const float* __restrict__ weights,
                             unsigned short* __restrict__ Wb,
                             float2* __restrict__ Wp) {
  const int idx = blockIdx.x * 256 + threadIdx.x;
  const int i4 = idx * 4;  // grid 192*256*4 = 196608 exact
  float4 v;
  if (i4 < 131072) v = *(const float4*)(enc_w + i4);
  else             v = *(const float4*)(dec_w + (i4 - 131072));
  unsigned int lo = pk_bf16(v.x, v.y), hi = pk_bf16(v.z, v.w);
  *(uint2*)(Wb + i4) = make_uint2(lo, hi);
  if (idx < 3072) {  // Wp[c2*24+m] = (w[2c2][m], w[2c2+1][m]); m 0..11 sin, 12..23 cos
    const int c2 = idx / 24, m = idx % 24;
    Wp[idx] = make_float2(weights[(2 * c2) * 24 + m], weights[(2 * c2 + 1) * 24 + m]);
  }
}

__device__ __forceinline__ float dot8(const float* q, uint4 a, uint4 b) {
  float s = 0.f;
  s = fmaf(q[0], blo(a.x), s); s = fmaf(q[1], bhi(a.x), s);
  s = fmaf(q[2], blo(a.y), s); s = fmaf(q[3], bhi(a.y), s);
  s = fmaf(q[4], blo(a.z), s); s = fmaf(q[5], bhi(a.z), s);
  s = fmaf(q[6], blo(a.w), s); s = fmaf(q[7], bhi(a.w), s);
  s = fmaf(q[8], blo(b.x), s); s = fmaf(q[9], bhi(b.x), s);
  s = fmaf(q[10], blo(b.y), s); s = fmaf(q[11], bhi(b.y), s);
  s = fmaf(q[12], blo(b.z), s); s = fmaf(q[13], bhi(b.z), s);
  s = fmaf(q[14], blo(b.w), s); s = fmaf(q[15], bhi(b.w), s);
  return s;
}
__device__ __forceinline__ void axpy8(float* o, float w, uint4 a, uint4 b) {
  o[0] = fmaf(w, blo(a.x), o[0]); o[1] = fmaf(w, bhi(a.x), o[1]);
  o[2] = fmaf(w, blo(a.y), o[2]); o[3] = fmaf(w, bhi(a.y), o[3]);
  o[4] = fmaf(w, blo(a.z), o[4]); o[5] = fmaf(w, bhi(a.z), o[5]);
  o[6] = fmaf(w, blo(a.w), o[6]); o[7] = fmaf(w, bhi(a.w), o[7]);
  o[8] = fmaf(w, blo(b.x), o[8]); o[9] = fmaf(w, bhi(b.x), o[9]);
  o[10] = fmaf(w, blo(b.y), o[10]); o[11] = fmaf(w, bhi(b.y), o[11]);
  o[12] = fmaf(w, blo(b.z), o[12]); o[13] = fmaf(w, bhi(b.z), o[13]);
  o[14] = fmaf(w, blo(b.w), o[14]); o[15] = fmaf(w, bhi(b.w), o[15]);
}

__global__ __launch_bounds__(512, 4) void nsb_kernel(
    const float* __restrict__ x,
    const float* __restrict__ latent,
    const float* __restrict__ enc_b,
    const float* __restrict__ dec_b,
    const unsigned short* __restrict__ Wb,
    const float2* __restrict__ Wp,
    float* __restrict__ out)
{
  __shared__ __attribute__((aligned(16))) unsigned char smem[SMEM_BYTES];
  const int t = threadIdx.x;
  const int wv = t >> 6, lane = t & 63;
  const int fm = lane & 15, quad = lane >> 4;
  const int bb = blockIdx.x >> 6;
  const int h0 = (blockIdx.x & 63) << 6;

  // ---------------- pass-1 GEMM: enc rows 0..511 ----------------
  f32x4 acc1[4][4];
#pragma unroll
  for (int i = 0; i < 4; ++i)
#pragma unroll
    for (int j = 0; j < 4; ++j) acc1[i][j] = f32x4{0.f, 0.f, 0.f, 0.f};

  const int arow = t >> 2, akq = t & 3;          // A staging
  const int bc2 = t & 31, bkp = t >> 5;          // B staging: kp 0..15, col-pair

  for (int kt = 0; kt < 8; ++kt) {
    const int k0 = kt << 5;
#pragma unroll
    for (int rd = 0; rd < 4; ++rd) {
      const int row = rd * 128 + arow;
      const uint4 w4 = *(const uint4*)(Wb + row * 256 + k0 + akq * 8);
      unsigned char* dst = smem + A1OFF + row * 72 + akq * 16;
      *(uint2*)(dst) = make_uint2(w4.x, w4.y);
      *(uint2*)(dst + 8) = make_uint2(w4.z, w4.w);
    }
    {
      const float* xr = x + (bb * 256 + k0 + 2 * bkp) * 4096 + h0 + bc2 * 2;
      const float2 x0 = *(const float2*)(xr);
      const float2 x1 = *(const float2*)(xr + 4096);
      unsigned int* bw = (unsigned int*)(smem + BOFF);
      bw[(bc2 * 2 + 0) * 18 + bkp] = pk_bf16(x0.x, x1.x);
      bw[(bc2 * 2 + 1) * 18 + bkp] = pk_bf16(x0.y, x1.y);
    }
    __syncthreads();
    short8 bfrag[4];
#pragma unroll
    for (int j = 0; j < 4; ++j) {
      const unsigned char* p = smem + BOFF + (j * 16 + fm) * 72 + quad * 16;
      union { short8 s; uint2 u[2]; } tb;
      tb.u[0] = *(const uint2*)(p); tb.u[1] = *(const uint2*)(p + 8);
      bfrag[j] = tb.s;
    }
#pragma unroll
    for (int i = 0; i < 4; ++i) {
      const unsigned char* p = smem + A1OFF + (wv * 64 + i * 16 + fm) * 72 + quad * 16;
      union { short8 s; uint2 u[2]; } ta;
      ta.u[0] = *(const uint2*)(p); ta.u[1] = *(const uint2*)(p + 8);
#pragma unroll
      for (int j = 0; j < 4; ++j)
        acc1[i][j] = __builtin_amdgcn_mfma_f32_16x16x32_bf16(ta.s, bfrag[j], acc1[i][j], 0, 0, 0);
    }
    __syncthreads();
  }

  // QL stage (fp32, [h][l][33])
  {
    const int e0 = t * 2;
    const float2 lv = *(const float2*)(latent + e0);
    const int h_ = e0 >> 7, l_ = (e0 >> 5) & 3, d_ = e0 & 31;
    float* ql = (float*)(smem + QLOFF) + (h_ * 4 + l_) * 33 + d_;
    ql[0] = lv.x; ql[1] = lv.y;
  }

  f32x4 acc2[2][4];
#pragma unroll
  for (int i = 0; i < 2; ++i)
#pragma unroll
    for (int j = 0; j < 4; ++j) acc2[i][j] = f32x4{0.f, 0.f, 0.f, 0.f};

  // epilogue lane roles
  const int hh = (lane >> 2) & 7, ll = lane & 3, dh2 = lane >> 5;

  auto doE = [&](int hf) {
    unsigned int* Ew = (unsigned int*)(smem + EOFF);
#pragma unroll
    for (int i = 0; i < 4; ++i) {
      const int rbase = wv * 64 + i * 16 + quad * 4;
      const float4 be = *(const float4*)(enc_b + rbase);
      const int d0 = i * 8 + quad * 2;
#pragma unroll
      for (int jj = 0; jj < 2; ++jj) {
        const int col = jj * 16 + fm;
        const int s0 = (d0 + 4 * wv + 8 * (col & 3)) & 31;   // even, <=30
        const f32x4 a = acc1[i][hf * 2 + jj];
        uint2 pr;
        pr.x = pk_bf16(a.x + be.x, a.y + be.y);   // rows (k,v) for d0
        pr.y = pk_bf16(a.z + be.z, a.w + be.w);   // rows (k,v) for d0+1
        *(uint2*)(Ew + col * 256 + wv * 32 + s0) = pr;
      }
    }
  };

  auto doAttn1Spectral = [&](int hf) {
    // ---- attn1: wave wv <-> patch wv; lane=(dh2,hh,ll) ----
    const unsigned int* Ew = (const unsigned int*)(smem + EOFF);
    const float* QLb = (const float*)(smem + QLOFF) + (hh * 4 + ll) * 33 + dh2 * 16;
    float qf[16];
#pragma unroll
    for (int j = 0; j < 16; ++j) qf[j] = QLb[j];
    float num[16];
#pragma unroll
    for (int j = 0; j < 16; ++j) num[j] = 0.f;
    float den = 0.f;
#pragma unroll
    for (int p = 0; p < 4; ++p) {
      const int col = wv * 4 + p;
      const unsigned int* Eb = Ew + col * 256 + hh * 32;
      uint4 kv[4];
#pragma unroll
      for (int jq = 0; jq < 4; ++jq) {
        const int off = (dh2 * 16 + jq * 4 + 4 * hh + 8 * p) & 31;
        kv[jq] = *(const uint4*)(Eb + off);
      }
      float sp = dot8(qf, kv[0], kv[1]) + dot8(qf + 8, kv[2], kv[3]);
      // wait: dot8 consumes 16 q's against 8 dwords; split correctly below
      sp = 0.f;
      {
        const unsigned int kd[16] = { kv[0].x, kv[0].y, kv[0].z, kv[0].w,
                                      kv[1].x, kv[1].y, kv[1].z, kv[1].w,
                                      kv[2].x, kv[2].y, kv[2].z, kv[2].w,
                                      kv[3].x, kv[3].y, kv[3].z, kv[3].w };
#pragma unroll
        for (int j = 0; j < 16; ++j) sp = fmaf(qf[j], blo(kd[j]), sp);
        sp += __shfl_xor(sp, 32);
        const float e = __expf(sp);
        den += e;
#pragma unroll
        for (int j = 0; j < 16; ++j) num[j] = fmaf(e, bhi(kd[j]), num[j]);
      }
    }
    const float inv = __builtin_amdgcn_rcpf(den);
    unsigned int* LTw = (unsigned int*)(smem + LTOFF) + wv * 528 + ll * 132 + hh * 16 + dh2 * 8;
    uint4 o0, o1;
    o0.x = pk_bf16(qf[0] + num[0] * inv, qf[1] + num[1] * inv);
    o0.y = pk_bf16(qf[2] + num[2] * inv, qf[3] + num[3] * inv);
    o0.z = pk_bf16(qf[4] + num[4] * inv, qf[5] + num[5] * inv);
    o0.w = pk_bf16(qf[6] + num[6] * inv, qf[7] + num[7] * inv);
    o1.x = pk_bf16(qf[8] + num[8] * inv, qf[9] + num[9] * inv);
    o1.y = pk_bf16(qf[10] + num[10] * inv, qf[11] + num[11] * inv);
    o1.z = pk_bf16(qf[12] + num[12] * inv, qf[13] + num[13] * inv);
    o1.w = pk_bf16(qf[14] + num[14] * inv, qf[15] + num[15] * inv);
    *(uint4*)(LTw) = o0;
    *(uint4*)(LTw + 4) = o1;

    // ---- spectral: in-place on LT patch wv; channel-pair packed ----
    unsigned int* LTp = (unsigned int*)(smem + LTOFF) + wv * 528;
#pragma unroll
    for (int cc = 0; cc < 2; ++cc) {
      const int c2 = cc * 64 + lane;
      const float2* wpp = Wp + c2 * 24;
      float2 wm[24];
#pragma unroll
      for (int m = 0; m < 24; m += 2) {
        const float4 w2 = *(const float4*)(wpp + m);
        wm[m] = make_float2(w2.x, w2.y);
        wm[m + 1] = make_float2(w2.z, w2.w);
      }
#pragma unroll
      for (int l = 0; l < 4; ++l) {
        unsigned int* ps = LTp + l * 132 + c2;
        const unsigned int pkv = *ps;
        const float vx = blo(pkv), vy = bhi(pkv);
        const float thx = vx * 0.26179938779914946f;
        const float thy = vy * 0.26179938779914946f;
        const float snx = __sinf(thx), csx = __cosf(thx);
        const float sny = __sinf(thy), csy = __cosf(thy);
        float avx = wm[12].x, avy = wm[12].y;
        float smx = snx, cmx = csx, smy = sny, cmy = csy;
#pragma unroll
        for (int m = 1; m <= 11; ++m) {
          avx = fmaf(wm[m].x, smx, fmaf(wm[12 + m].x, cmx, avx));
          avy = fmaf(wm[m].y, smy, fmaf(wm[12 + m].y, cmy, avy));
          if (m < 11) {
            const float nsx = fmaf(smx, csx, cmx * snx);
            cmx = fmaf(cmx, csx, -(smx * snx)); smx = nsx;
            const float nsy = fmaf(smy, csy, cmy * sny);
            cmy = fmaf(cmy, csy, -(smy * sny)); smy = nsy;
          }
        }
        *ps = pk_bf16(avx + vx, avy + vy);
      }
    }
  };

  auto doD = [&](int hf) {
    unsigned int* Dw = (unsigned int*)(smem + DOFF);
#pragma unroll
    for (int i2 = 0; i2 < 2; ++i2) {
      const int ch0 = wv * 32 + i2 * 16 + quad * 4;
      const float4 bd = *(const float4*)(dec_b + ch0);
      const int cd0 = ch0 >> 1;  // even
#pragma unroll
      for (int jj = 0; jj < 2; ++jj) {
        const int colh = jj * 16 + fm;
        const f32x4 a = acc2[i2][hf * 2 + jj];
        uint2 pr;
        pr.x = pk_bf16(a.x + bd.x, a.y + bd.y);
        pr.y = pk_bf16(a.z + bd.z, a.w + bd.w);
        *(uint2*)(Dw + colh * 132 + cd0) = pr;
      }
    }
  };

  auto doAttn2 = [&](int hf) {
    const int pp = ll;  // lane=(dh2,hh,pp)
    const int colh = wv * 4 + pp;
    const unsigned int* Dq = (const unsigned int*)(smem + DOFF) + colh * 132 + hh * 16 + dh2 * 8;
    const uint4 d0 = *(const uint4*)(Dq);
    const uint4 d1 = *(const uint4*)(Dq + 4);
    float dqf[16];
    dqf[0] = blo(d0.x); dqf[1] = bhi(d0.x); dqf[2] = blo(d0.y); dqf[3] = bhi(d0.y);
    dqf[4] = blo(d0.z); dqf[5] = bhi(d0.z); dqf[6] = blo(d0.w); dqf[7] = bhi(d0.w);
    dqf[8] = blo(d1.x); dqf[9] = bhi(d1.x); dqf[10] = blo(d1.y); dqf[11] = bhi(d1.y);
    dqf[12] = blo(d1.z); dqf[13] = bhi(d1.z); dqf[14] = blo(d1.w); dqf[15] = bhi(d1.w);
    const unsigned int* LTw = (const unsigned int*)(smem + LTOFF) + wv * 528 + hh * 16 + dh2 * 8;
    float aw[4]; float den = 0.f;
#pragma unroll
    for (int l = 0; l < 4; ++l) {
      const uint4 l0 = *(const uint4*)(LTw + l * 132);
      const uint4 l1 = *(const uint4*)(LTw + l * 132 + 4);
      float s = dot8(dqf, l0, l1);
      // dot8 handles dwords l0(4)+l1(4) against dqf[0..15] pairwise
      s += __shfl_xor(s, 32);
      const float e = __expf(s);
      aw[l] = e; den += e;
    }
    const float inv = __builtin_amdgcn_rcpf(den);
#pragma unroll
    for (int l = 0; l < 4; ++l) aw[l] *= inv;
    float ov[16];
#pragma unroll
    for (int j = 0; j < 16; ++j) ov[j] = 0.f;
#pragma unroll
    for (int l = 0; l < 4; ++l) {
      const uint4 l0 = *(const uint4*)(LTw + l * 132);
      const uint4 l1 = *(const uint4*)(LTw + l * 132 + 4);
      axpy8(ov, aw[l], l0, l1);
    }
    const int hp = (blockIdx.x & 63) * 16 + hf * 8 + wv;
    const int hg = h0 + hf * 32 + wv * 4 + pp;
    const float* xc = x + bb * 1048576 + (hh * 32 + dh2 * 16) * 4096 + hg;
#pragma unroll
    for (int j = 0; j < 16; ++j) ov[j] += xc[j * 4096];
    float* ob = out + bb * 1048576 + pp * 262144 + hp * 256 + hh * 32 + dh2 * 16;
    *(float4*)(ob + 0) = make_float4(ov[0], ov[1], ov[2], ov[3]);
    *(float4*)(ob + 4) = make_float4(ov[4], ov[5], ov[6], ov[7]);
    *(float4*)(ob + 8) = make_float4(ov[8], ov[9], ov[10], ov[11]);
    *(float4*)(ob + 12) = make_float4(ov[12], ov[13], ov[14], ov[15]);
  };

  // ---------------- sequence ----------------
  doE(0);
  __syncthreads();
  doAttn1Spectral(0);
  __syncthreads();

  // pass-2 GEMM: dec rows 512..767 (A2 overlays dead E; B still resident)
  for (int kt = 0; kt < 8; ++kt) {
    const int k0 = kt << 5;
#pragma unroll
    for (int rd = 0; rd < 2; ++rd) {
      const int row = rd * 128 + arow;
      const uint4 w4 = *(const uint4*)(Wb + (512 + row) * 256 + k0 + akq * 8);
      unsigned char* dst = smem + A2OFF + row * 72 + akq * 16;
      *(uint2*)(dst) = make_uint2(w4.x, w4.y);
      *(uint2*)(dst + 8) = make_uint2(w4.z, w4.w);
    }
    __syncthreads();
    short8 bfrag[4];
#pragma unroll
    for (int j = 0; j < 4; ++j) {
      const unsigned char* p = smem + BOFF + (j * 16 + fm) * 72 + quad * 16;
      union { short8 s; uint2 u[2]; } tb;
      tb.u[0] = *(const uint2*)(p); tb.u[1] = *(const uint2*)(p + 8);
      bfrag[j] = tb.s;
    }
#pragma unroll
    for (int i = 0; i < 2; ++i) {
      const unsigned char* p = smem + A2OFF + (wv * 32 + i * 16 + fm) * 72 + quad * 16;
      union { short8 s; uint2 u[2]; } ta;
      ta.u[0] = *(const uint2*)(p); ta.u[1] = *(const uint2*)(p + 8);
#pragma unroll
      for (int j = 0; j < 4; ++j)
        acc2[i][j] = __builtin_amdgcn_mfma_f32_16x16x32_bf16(ta.s, bfrag[j], acc2[i][j], 0, 0, 0);
    }
    __syncthreads();
  }

  doD(0);
  __syncthreads();
  doAttn2(0);
  __syncthreads();

  doE(1);
  __syncthreads();
  doAttn1Spectral(1);
  __syncthreads();
  doD(1);
  __syncthreads();
  doAttn2(1);
}

extern "C" void kernel_launch(void* const* d_in, const int* in_sizes, int n_in,
                              void* d_out, int out_size, void* d_ws, size_t ws_size,
                              hipStream_t stream) {
  const float* x       = (const float*)d_in[0];
  const float* weights = (const float*)d_in[1];
  const float* latent  = (const float*)d_in[2];
  const float* enc_w   = (const float*)d_in[3];
  const float* enc_b   = (const float*)d_in[4];
  const float* dec_w   = (const float*)d_in[5];
  const float* dec_b   = (const float*)d_in[6];
  unsigned short* Wb   = (unsigned short*)d_ws;                       // 384 KB
  float2* Wp           = (float2*)((char*)d_ws + 393216);             // 24 KB
  float* outp          = (float*)d_out;

  wconv_kernel<<<192, 256, 0, stream>>>(enc_w, dec_w, weights, Wb, Wp);
  nsb_kernel<<<2048, 512, 0, stream>>>(x, latent, enc_b, dec_b, Wb, (const float2*)Wp, outp);
}